// Round 5
// baseline (206.075 us; speedup 1.0000x reference)
//
#include <hip/hip_runtime.h>
#include <hip/hip_bf16.h>
#include <math.h>

#define B_ 16
#define C_ 64
#define N_ 4096   // 64*64 pixels
#define M_ 1024   // 32*32 pooled keys

typedef __attribute__((ext_vector_type(8))) short v8s;   // 8 bf16 (4 VGPRs)
typedef __attribute__((ext_vector_type(4))) short v4s;   // 4 bf16 (2 VGPRs)
typedef __attribute__((ext_vector_type(4))) float v4f;   // 4 fp32 acc

__device__ inline unsigned short f2bf(float f) {
    __hip_bfloat16 h = __float2bfloat16(f);
    return *(unsigned short*)&h;
}
__device__ inline unsigned pack2bf(float a, float b) {
    return (unsigned)f2bf(a) | ((unsigned)f2bf(b) << 16);
}
__device__ inline v8s cvt8(float4 a, float4 b) {
    union { v8s v; unsigned u[4]; } r;
    r.u[0] = pack2bf(a.x, a.y);
    r.u[1] = pack2bf(a.z, a.w);
    r.u[2] = pack2bf(b.x, b.y);
    r.u[3] = pack2bf(b.z, b.w);
    return r.v;
}
__device__ inline v4s cvt4(float4 a) {
    union { v4s v; unsigned u[2]; } r;
    r.u[0] = pack2bf(a.x, a.y);
    r.u[1] = pack2bf(a.z, a.w);
    return r.v;
}

// K=16 bf16 MFMA: A[m=l15][k=l4*4+j], B[k=l4*4+j][n=l15],
// C/D: col=l15, row=l4*4+reg (16x16-family layout).
__device__ inline v4f mfma16(v4s a, v4s b, v4f c) {
#if __has_builtin(__builtin_amdgcn_mfma_f32_16x16x16bf16_1k)
    return __builtin_amdgcn_mfma_f32_16x16x16bf16_1k(a, b, c, 0, 0, 0);
#else
    v4f d;
    asm("v_mfma_f32_16x16x16_bf16 %0, %1, %2, %3\n\ts_nop 7\n\ts_nop 7"
        : "=&v"(d) : "v"(a), "v"(b), "v"(c));
    return d;
#endif
}

// ---------------------------------------------------------------------------
// Kernel 1 (unchanged from round 8 / reverted round-1 structure).
// ---------------------------------------------------------------------------
#define SP2 66   // sPool row stride (floats)

__global__ __launch_bounds__(256, 2) void conv_pool_k(
    const float* __restrict__ x,
    const float* __restrict__ Wt, const float* __restrict__ bt,
    const float* __restrict__ Wp, const float* __restrict__ bp,
    const float* __restrict__ Wg, const float* __restrict__ bg,
    unsigned short* __restrict__ thetaT,
    unsigned short* __restrict__ phiT,
    unsigned short* __restrict__ gcm)
{
    __shared__ float sPool[80 * SP2];   // 40 ch x 2 rows = 80 rows, 21.1 KB

    const int tid  = threadIdx.x;
    const int lane = tid & 63;
    const int wid  = tid >> 6;
    const int l15  = lane & 15;
    const int l4   = lane >> 4;

    const int b  = blockIdx.x >> 5;
    const int y0 = (blockIdx.x & 31) << 1;   // first of 2 image rows
    const int y  = y0 + (wid >> 1);          // this wave's row
    const int xh = (wid & 1) * 32;           // this wave's half-row

    // --- A-fragments: weights, 3 m-tiles x 2 k-halves (bf16, loaded once)
    const float* row0 = (l15 < 8) ? (Wt + l15 * 64) : (Wp + (l15 - 8) * 64);
    const float* row1 = Wg + l15 * 64;
    const float* row2 = Wg + (16 + l15) * 64;
    v8s afrag[3][2];
    #pragma unroll
    for (int kh = 0; kh < 2; ++kh) {
        const int c0 = kh * 32 + l4 * 8;
        afrag[0][kh] = cvt8(*(const float4*)(row0 + c0), *(const float4*)(row0 + c0 + 4));
        afrag[1][kh] = cvt8(*(const float4*)(row1 + c0), *(const float4*)(row1 + c0 + 4));
        afrag[2][kh] = cvt8(*(const float4*)(row2 + c0), *(const float4*)(row2 + c0 + 4));
    }

    // --- accumulators init = bias (C-layout: row o = l4*4+r)
    v4f acc[2][3];
    {
        float bv[3][4];
        #pragma unroll
        for (int r = 0; r < 4; ++r) {
            const int o = l4 * 4 + r;               // 0..15
            bv[0][r] = (o < 8) ? bt[o] : bp[o - 8];
            bv[1][r] = bg[o];
            bv[2][r] = bg[16 + o];
        }
        #pragma unroll
        for (int nt = 0; nt < 2; ++nt)
            #pragma unroll
            for (int t = 0; t < 3; ++t) {
                v4f a; a[0] = bv[t][0]; a[1] = bv[t][1];
                a[2] = bv[t][2]; a[3] = bv[t][3];
                acc[nt][t] = a;
            }
    }

    // --- main GEMM: 2 n-tiles x 2 k-halves x 3 m-tiles
    const float* xb = x + (size_t)b * C_ * N_ + y * 64;
    #pragma unroll
    for (int nt = 0; nt < 2; ++nt) {
        const int n0 = xh + nt * 16 + l15;
        #pragma unroll
        for (int kh = 0; kh < 2; ++kh) {
            const int cb = kh * 32 + l4 * 8;
            float f[8];
            #pragma unroll
            for (int j = 0; j < 8; ++j) f[j] = xb[(size_t)(cb + j) * N_ + n0];
            union { v8s v; unsigned u[4]; } bf;
            #pragma unroll
            for (int j = 0; j < 4; ++j) bf.u[j] = pack2bf(f[2*j], f[2*j+1]);
            #pragma unroll
            for (int t = 0; t < 3; ++t)
                acc[nt][t] = __builtin_amdgcn_mfma_f32_16x16x32_bf16(
                    afrag[t][kh], bf.v, acc[nt][t], 0, 0, 0);
        }
    }

    // --- theta: straight from C-regs (rows 0..7 of m-tile 0 = lanes l4<2)
    #pragma unroll
    for (int nt = 0; nt < 2; ++nt) {
        if (l4 < 2) {
            const int n = y * 64 + xh + nt * 16 + l15;
            const unsigned lo = pack2bf(acc[nt][0][0], acc[nt][0][1]);
            const unsigned hi = pack2bf(acc[nt][0][2], acc[nt][0][3]);
            *(uint2*)(thetaT + ((size_t)b * N_ + n) * 8 + l4 * 4) = make_uint2(lo, hi);
        }
    }

    // --- stage phi/g to LDS for pooling: row index = ch*2 + (image row in pair)
    {
        const int rr = wid >> 1;   // 0/1: which row of the pair
        #pragma unroll
        for (int nt = 0; nt < 2; ++nt) {
            const int px = xh + nt * 16 + l15;      // 0..63
            if (l4 >= 2) {                          // phi: ch = (l4-2)*4 + r
                #pragma unroll
                for (int r = 0; r < 4; ++r)
                    sPool[(((l4 - 2) * 4 + r) * 2 + rr) * SP2 + px] = acc[nt][0][r];
            }
            #pragma unroll
            for (int r = 0; r < 4; ++r) {
                sPool[((8  + l4 * 4 + r) * 2 + rr) * SP2 + px] = acc[nt][1][r];
                sPool[((24 + l4 * 4 + r) * 2 + rr) * SP2 + px] = acc[nt][2][r];
            }
        }
    }
    __syncthreads();

    // --- 2x2 maxpool + store: 40 ch x 32 pooled px per block
    {
        const int pc  = tid & 31;          // pooled col
        const int grp = tid >> 5;          // 8 groups x 5 channels
        const int mg  = (y0 >> 1) * 32 + pc;
        #pragma unroll
        for (int i = 0; i < 5; ++i) {
            const int ch = grp * 5 + i;
            const float* s0 = sPool + (ch * 2 + 0) * SP2 + pc * 2;
            const float* s1 = sPool + (ch * 2 + 1) * SP2 + pc * 2;
            const float v = fmaxf(fmaxf(s0[0], s0[1]), fmaxf(s1[0], s1[1]));
            if (ch < 8) phiT[((size_t)b * M_ + mg) * 8 + ch] = f2bf(v);
            else        gcm[((size_t)(b * 32 + ch - 8)) * M_ + mg] = f2bf(v);
        }
    }
}

// ---------------------------------------------------------------------------
// Kernel 2 (round 9): register-pipelined direct-L2 attention.
// R3->R4 lesson: concurrency/SIMD was invariant at 4 chains (waves x streams),
// and each 16-key chunk is a ~300cy dependent chain with ~60cy issue -> 37us.
// Fix: per-wave MLP.  Batches of 4 chunks; buf[2][4] explicit double buffer
// (static indices -> registers, rule #20); batch t+1's 12 independent
// dwordx2 loads issue BEFORE batch t's compute.  12 loads always in flight
// per wave; ~250cy compute/batch covers L2 latency (~200-300cy).  No LDS,
// no barriers.  phi/g are L2-resident (80KB/batch).  Wo/bo/gamma loads
// moved to epilogue (VGPR pressure).  Grid 1024, 4 waves/SIMD, <=128 VGPR.
// Even/odd chunk acc pairs break the PV accumulator chain.
// phi rows are 8 shorts; lanes l4>=2 read (l4&1)*4 dup (theta B-frag is
// zero for k>=8 -> contributes 0; values finite).  Proven in R3/R4.
// ---------------------------------------------------------------------------
__global__ __launch_bounds__(256, 4) void attn_k(
    const float* __restrict__ x,
    const unsigned short* __restrict__ thetaT,
    const unsigned short* __restrict__ phiT,
    const unsigned short* __restrict__ gcm,
    const float* __restrict__ Wo, const float* __restrict__ bo,
    const float* __restrict__ gammap,
    float* __restrict__ out)
{
    const int tid  = threadIdx.x;
    const int lane = tid & 63;
    const int wid  = tid >> 6;
    const int l15  = lane & 15;
    const int l4   = lane >> 4;

    const int b  = blockIdx.x >> 6;
    const int qw = ((blockIdx.x & 63) << 6) + wid * 16;   // 16 queries/wave

    // --- theta B-frag (K=16: k=ch l4*4+j, real for l4<2, zero else)
    v4s bth; { v4s z = {}; bth = z; }
    if (l4 < 2)
        bth = *(const v4s*)(thetaT + ((size_t)b * N_ + qw + l15) * 8 + l4 * 4);

    // --- per-lane base pointers for the chunk loads
    const unsigned short* phB = phiT + (size_t)b * M_ * 8 + l15 * 8 + (l4 & 1) * 4;
    const unsigned short* g0B = gcm + ((size_t)(b * 32) + l15) * M_ + l4 * 4;
    const unsigned short* g1B = g0B + 16 * M_;

    // --- explicit register double buffer: 4 chunks/batch x 3 frags
    v4s bufP[2][4], bufG0[2][4], bufG1[2][4];

#define LOADB(bi, bt)                                                   \
    {                                                                   \
        _Pragma("unroll")                                               \
        for (int c = 0; c < 4; ++c) {                                   \
            const int kk = (bt) * 4 + c;                                \
            bufP [bi][c] = *(const v4s*)(phB + kk * 128);               \
            bufG0[bi][c] = *(const v4s*)(g0B + kk * 16);                \
            bufG1[bi][c] = *(const v4s*)(g1B + kk * 16);                \
        }                                                               \
    }

    v4f accA0, accA1, accB0, accB1;
    { v4f z = {}; accA0 = z; accA1 = z; accB0 = z; accB1 = z; }
    float lsum = 0.f;
    const v4f zf = {};

    LOADB(0, 0);
    #pragma unroll
    for (int bt = 0; bt < 16; ++bt) {        // 16 batches of 4 chunks
        if (bt < 15) LOADB((bt + 1) & 1, bt + 1);
        #pragma unroll
        for (int c = 0; c < 4; ++c) {
            const int bi = bt & 1;
            v4f s = mfma16(bufP[bi][c], bth, zf);
            const float e0 = __expf(s[0]), e1 = __expf(s[1]);
            const float e2 = __expf(s[2]), e3 = __expf(s[3]);
            lsum += (e0 + e1) + (e2 + e3);
            union { v4s v; unsigned u[2]; } p;
            p.u[0] = pack2bf(e0, e1);
            p.u[1] = pack2bf(e2, e3);
            if (c & 1) {
                accB0 = mfma16(bufG0[bi][c], p.v, accB0);
                accB1 = mfma16(bufG1[bi][c], p.v, accB1);
            } else {
                accA0 = mfma16(bufG0[bi][c], p.v, accA0);
                accA1 = mfma16(bufG1[bi][c], p.v, accA1);
            }
        }
    }
#undef LOADB

    v4f acc0 = accA0 + accB0;                // O[c=l4*4+r][q=l15], c-tile 0
    v4f acc1 = accA1 + accB1;                // c-tile 1 (c+16)

    // --- softmax denominator: sum over the 4 l4-groups sharing query l15
    float v = lsum;
    v += __shfl_xor(v, 16);
    v += __shfl_xor(v, 32);
    const float rl = 1.0f / v;

    // --- normalize + pack O -> B-frags of the output-conv MFMA (k=c=l4*4+j)
    v4s pO0, pO1;
    {
        union { v4s v; unsigned u[2]; } p;
        p.u[0] = pack2bf(acc0[0] * rl, acc0[1] * rl);
        p.u[1] = pack2bf(acc0[2] * rl, acc0[3] * rl);
        pO0 = p.v;
        p.u[0] = pack2bf(acc1[0] * rl, acc1[1] * rl);
        p.u[1] = pack2bf(acc1[2] * rl, acc1[3] * rl);
        pO1 = p.v;
    }

    // --- output conv via 8 K=16 MFMAs + residual.  Wo/bo loaded HERE
    // (off the main loop's register budget).  D[m=oc][n=q], bias in C-init.
    const float gamma = *gammap;
    const size_t colq = qw + l15;
    #pragma unroll
    for (int mt = 0; mt < 4; ++mt) {
        const int oc0 = mt * 16 + l4 * 4;
        const float4 w0 = *(const float4*)(Wo + (mt * 16 + l15) * 32 + l4 * 4);
        const float4 w1 = *(const float4*)(Wo + (mt * 16 + l15) * 32 + 16 + l4 * 4);
        const float4 bo4 = *(const float4*)(bo + oc0);
        v4f c; c[0] = bo4.x; c[1] = bo4.y; c[2] = bo4.z; c[3] = bo4.w;
        c = mfma16(cvt4(w0), pO0, c);
        c = mfma16(cvt4(w1), pO1, c);
        const float* xr   = x   + ((size_t)(b * 64 + oc0)) * N_ + colq;
        float*       orow = out + ((size_t)(b * 64 + oc0)) * N_ + colq;
        #pragma unroll
        for (int r = 0; r < 4; ++r)
            orow[(size_t)r * N_] = gamma * c[r] + xr[(size_t)r * N_];
    }
}

// ---------------------------------------------------------------------------
extern "C" void kernel_launch(void* const* d_in, const int* in_sizes, int n_in,
                              void* d_out, int out_size, void* d_ws, size_t ws_size,
                              hipStream_t stream) {
    const float* x  = (const float*)d_in[0];
    const float* Wt = (const float*)d_in[1];
    const float* bt = (const float*)d_in[2];
    const float* Wp = (const float*)d_in[3];
    const float* bp = (const float*)d_in[4];
    const float* Wg = (const float*)d_in[5];
    const float* bg = (const float*)d_in[6];
    const float* Wo = (const float*)d_in[7];
    const float* bo = (const float*)d_in[8];
    const float* gm = (const float*)d_in[9];
    float* out = (float*)d_out;

    // workspace (bf16): thetaT [16][4096][8] | phiT [16][1024][8] | gcm [16][32][1024]
    unsigned short* thetaT = (unsigned short*)d_ws;
    unsigned short* phiT   = thetaT + (size_t)B_ * N_ * 8;
    unsigned short* gcm    = phiT   + (size_t)B_ * M_ * 8;

    hipLaunchKernelGGL(conv_pool_k, dim3(512), dim3(256), 0, stream,
                       x, Wt, bt, Wp, bp, Wg, bg, thetaT, phiT, gcm);
    hipLaunchKernelGGL(attn_k, dim3(1024), dim3(256), 0, stream,
                       x, thetaT, phiT, gcm, Wo, bo, gm, out);
}

// Round 6
// 111.466 us; speedup vs baseline: 1.8488x; 1.8488x over previous
//
#include <hip/hip_runtime.h>
#include <hip/hip_bf16.h>
#include <math.h>

#define B_ 16
#define C_ 64
#define N_ 4096   // 64*64 pixels
#define M_ 1024   // 32*32 pooled keys

typedef __attribute__((ext_vector_type(8))) short v8s;   // 8 bf16 (4 VGPRs)
typedef __attribute__((ext_vector_type(4))) short v4s;   // 4 bf16 (2 VGPRs)
typedef __attribute__((ext_vector_type(4))) float v4f;   // 4 fp32 acc

__device__ inline unsigned short f2bf(float f) {
    __hip_bfloat16 h = __float2bfloat16(f);
    return *(unsigned short*)&h;
}
__device__ inline unsigned pack2bf(float a, float b) {
    return (unsigned)f2bf(a) | ((unsigned)f2bf(b) << 16);
}
__device__ inline v8s cvt8(float4 a, float4 b) {
    union { v8s v; unsigned u[4]; } r;
    r.u[0] = pack2bf(a.x, a.y);
    r.u[1] = pack2bf(a.z, a.w);
    r.u[2] = pack2bf(b.x, b.y);
    r.u[3] = pack2bf(b.z, b.w);
    return r.v;
}
__device__ inline v4s cvt4(float4 a) {
    union { v4s v; unsigned u[2]; } r;
    r.u[0] = pack2bf(a.x, a.y);
    r.u[1] = pack2bf(a.z, a.w);
    return r.v;
}

// K=16 bf16 MFMA: A[m=l15][k=l4*4+j], B[k=l4*4+j][n=l15],
// C/D: col=l15, row=l4*4+reg (16x16-family layout).
__device__ inline v4f mfma16(v4s a, v4s b, v4f c) {
#if __has_builtin(__builtin_amdgcn_mfma_f32_16x16x16bf16_1k)
    return __builtin_amdgcn_mfma_f32_16x16x16bf16_1k(a, b, c, 0, 0, 0);
#else
    v4f d;
    asm("v_mfma_f32_16x16x16_bf16 %0, %1, %2, %3\n\ts_nop 7\n\ts_nop 7"
        : "=&v"(d) : "v"(a), "v"(b), "v"(c));
    return d;
#endif
}

// ---------------------------------------------------------------------------
// Kernel 1 (round 10): R4 structure + LDS-staged x-tile.
// R4's inner loop issued 96 channel-strided scalar HBM loads per lane
// (16KB stride, ~600cy each, only 2 waves/SIMD of cover).  Now: stage the
// block's x-tile (64ch x 2rows x 64px = 32KB) via coalesced float4 loads
// (8/thread, all issued before any ds_write - T14), then feed MFMA from
// ds_read (~120cy, pipelined).  Channel stride 133 floats -> l4 groups 8
// banks apart -> 2-way conflicts (free, m136).  LDS 34+21.1=55KB, 2 blk/CU.
// ---------------------------------------------------------------------------
#define SP2 66        // sPool row stride (floats)
#define XST 133       // sX per-channel stride (floats): 2 rows of 66

__global__ __launch_bounds__(256, 2) void conv_pool_k(
    const float* __restrict__ x,
    const float* __restrict__ Wt, const float* __restrict__ bt,
    const float* __restrict__ Wp, const float* __restrict__ bp,
    const float* __restrict__ Wg, const float* __restrict__ bg,
    unsigned short* __restrict__ thetaT,
    unsigned short* __restrict__ phiT,
    unsigned short* __restrict__ gcm)
{
    __shared__ float sX[64 * XST];      // 34.0 KB staged x-tile
    __shared__ float sPool[80 * SP2];   // 21.1 KB pooling slab

    const int tid  = threadIdx.x;
    const int lane = tid & 63;
    const int wid  = tid >> 6;
    const int l15  = lane & 15;
    const int l4   = lane >> 4;

    const int b  = blockIdx.x >> 5;
    const int y0 = (blockIdx.x & 31) << 1;   // first of 2 image rows
    const int rr = wid >> 1;                 // this wave's row-in-pair
    const int y  = y0 + rr;
    const int xh = (wid & 1) * 32;           // this wave's half-row

    // --- stage x-tile: issue all 8 coalesced float4 loads, then write LDS
    {
        const float* xb2 = x + (size_t)b * C_ * N_ + y0 * 64;
        float4 rx[8];
        #pragma unroll
        for (int k = 0; k < 8; ++k) {
            const int i = tid + k * 256;           // 0..2047
            rx[k] = *(const float4*)(xb2 + (size_t)(i >> 5) * N_
                                     + ((i >> 4) & 1) * 64 + (i & 15) * 4);
        }
        #pragma unroll
        for (int k = 0; k < 8; ++k) {
            const int i = tid + k * 256;
            *(float4*)&sX[(i >> 5) * XST + ((i >> 4) & 1) * 66 + (i & 15) * 4] = rx[k];
        }
    }

    // --- A-fragments: weights, 3 m-tiles x 2 k-halves (bf16, loaded once)
    const float* row0 = (l15 < 8) ? (Wt + l15 * 64) : (Wp + (l15 - 8) * 64);
    const float* row1 = Wg + l15 * 64;
    const float* row2 = Wg + (16 + l15) * 64;
    v8s afrag[3][2];
    #pragma unroll
    for (int kh = 0; kh < 2; ++kh) {
        const int c0 = kh * 32 + l4 * 8;
        afrag[0][kh] = cvt8(*(const float4*)(row0 + c0), *(const float4*)(row0 + c0 + 4));
        afrag[1][kh] = cvt8(*(const float4*)(row1 + c0), *(const float4*)(row1 + c0 + 4));
        afrag[2][kh] = cvt8(*(const float4*)(row2 + c0), *(const float4*)(row2 + c0 + 4));
    }

    // --- accumulators init = bias (C-layout: row o = l4*4+r)
    v4f acc[2][3];
    {
        float bv[3][4];
        #pragma unroll
        for (int r = 0; r < 4; ++r) {
            const int o = l4 * 4 + r;               // 0..15
            bv[0][r] = (o < 8) ? bt[o] : bp[o - 8];
            bv[1][r] = bg[o];
            bv[2][r] = bg[16 + o];
        }
        #pragma unroll
        for (int nt = 0; nt < 2; ++nt)
            #pragma unroll
            for (int t = 0; t < 3; ++t) {
                v4f a; a[0] = bv[t][0]; a[1] = bv[t][1];
                a[2] = bv[t][2]; a[3] = bv[t][3];
                acc[nt][t] = a;
            }
    }

    __syncthreads();   // x-tile ready

    // --- main GEMM: 2 n-tiles x 2 k-halves x 3 m-tiles, B-frags from LDS
    #pragma unroll
    for (int nt = 0; nt < 2; ++nt) {
        const int n0 = xh + nt * 16 + l15;
        #pragma unroll
        for (int kh = 0; kh < 2; ++kh) {
            const int cb = kh * 32 + l4 * 8;
            float f[8];
            #pragma unroll
            for (int j = 0; j < 8; ++j)
                f[j] = sX[(cb + j) * XST + rr * 66 + n0];
            union { v8s v; unsigned u[4]; } bf;
            #pragma unroll
            for (int j = 0; j < 4; ++j) bf.u[j] = pack2bf(f[2*j], f[2*j+1]);
            #pragma unroll
            for (int t = 0; t < 3; ++t)
                acc[nt][t] = __builtin_amdgcn_mfma_f32_16x16x32_bf16(
                    afrag[t][kh], bf.v, acc[nt][t], 0, 0, 0);
        }
    }

    // --- theta: straight from C-regs (rows 0..7 of m-tile 0 = lanes l4<2)
    #pragma unroll
    for (int nt = 0; nt < 2; ++nt) {
        if (l4 < 2) {
            const int n = y * 64 + xh + nt * 16 + l15;
            const unsigned lo = pack2bf(acc[nt][0][0], acc[nt][0][1]);
            const unsigned hi = pack2bf(acc[nt][0][2], acc[nt][0][3]);
            *(uint2*)(thetaT + ((size_t)b * N_ + n) * 8 + l4 * 4) = make_uint2(lo, hi);
        }
    }

    // --- stage phi/g to LDS for pooling: row index = ch*2 + (row-in-pair)
    {
        #pragma unroll
        for (int nt = 0; nt < 2; ++nt) {
            const int px = xh + nt * 16 + l15;      // 0..63
            if (l4 >= 2) {                          // phi: ch = (l4-2)*4 + r
                #pragma unroll
                for (int r = 0; r < 4; ++r)
                    sPool[(((l4 - 2) * 4 + r) * 2 + rr) * SP2 + px] = acc[nt][0][r];
            }
            #pragma unroll
            for (int r = 0; r < 4; ++r) {
                sPool[((8  + l4 * 4 + r) * 2 + rr) * SP2 + px] = acc[nt][1][r];
                sPool[((24 + l4 * 4 + r) * 2 + rr) * SP2 + px] = acc[nt][2][r];
            }
        }
    }
    __syncthreads();

    // --- 2x2 maxpool + store: 40 ch x 32 pooled px per block
    {
        const int pc  = tid & 31;          // pooled col
        const int grp = tid >> 5;          // 8 groups x 5 channels
        const int mg  = (y0 >> 1) * 32 + pc;
        #pragma unroll
        for (int i = 0; i < 5; ++i) {
            const int ch = grp * 5 + i;
            const float* s0 = sPool + (ch * 2 + 0) * SP2 + pc * 2;
            const float* s1 = sPool + (ch * 2 + 1) * SP2 + pc * 2;
            const float v = fmaxf(fmaxf(s0[0], s0[1]), fmaxf(s1[0], s1[1]));
            if (ch < 8) phiT[((size_t)b * M_ + mg) * 8 + ch] = f2bf(v);
            else        gcm[((size_t)(b * 32 + ch - 8)) * M_ + mg] = f2bf(v);
        }
    }
}

// ---------------------------------------------------------------------------
// Kernel 2: EXACT revert to round-8 (R4) attn — measured 37us, passed.
// (R5's register double-buffer went to scratch: unroll refused -> runtime
// bi -> 290MB spill traffic.  Reverted.)
// ---------------------------------------------------------------------------
#define P2_SZ  (128 * 8)      // shorts per phi buffer (row = 8 shorts)
#define G2_STR 136            // g row stride in shorts (272 B -> 2-way banks)
#define G2_SZ  (32 * G2_STR)  // shorts per g buffer

__global__ __launch_bounds__(256, 4) void attn_k(
    const float* __restrict__ x,
    const unsigned short* __restrict__ thetaT,
    const unsigned short* __restrict__ phiT,
    const unsigned short* __restrict__ gcm,
    const float* __restrict__ Wo, const float* __restrict__ bo,
    const float* __restrict__ gammap,
    float* __restrict__ out)
{
    __shared__ unsigned short phiL[2 * P2_SZ];   // 4 KB
    __shared__ unsigned short gL[2 * G2_SZ];     // 17.4 KB

    const int tid  = threadIdx.x;
    const int lane = tid & 63;
    const int wid  = tid >> 6;
    const int l15  = lane & 15;
    const int l4   = lane >> 4;

    const int b  = blockIdx.x >> 6;
    const int qw = ((blockIdx.x & 63) << 6) + wid * 16;   // 16 queries/wave

    // --- theta B-frag (K=16: k=ch l4*4+j, real for l4<2, zero else)
    v4s bth; { v4s z = {}; bth = z; }
    if (l4 < 2)
        bth = *(const v4s*)(thetaT + ((size_t)b * N_ + qw + l15) * 8 + l4 * 4);

    // --- Wo A-frags + gamma hoisted off the critical tail
    v4s wA[4][2];
    #pragma unroll
    for (int mt = 0; mt < 4; ++mt) {
        const float4 w0 = *(const float4*)(Wo + (mt * 16 + l15) * 32 + l4 * 4);
        const float4 w1 = *(const float4*)(Wo + (mt * 16 + l15) * 32 + 16 + l4 * 4);
        wA[mt][0] = cvt4(w0);
        wA[mt][1] = cvt4(w1);
    }
    const float gamma = *gammap;

    // --- staging addresses (per thread)
    const unsigned short* phSrc = phiT + ((size_t)b * M_ + (tid >> 1)) * 8 + (tid & 1) * 4;
    const int phOff = (tid >> 1) * 8 + (tid & 1) * 4;
    const int gch = tid >> 3, gseg = (tid & 7) * 16;
    const unsigned short* gSrc = gcm + ((size_t)(b * 32 + gch)) * M_ + gseg;
    const int gOff = gch * G2_STR + gseg;

    // --- prologue: load + write tile 0
    uint2 r_ph = *(const uint2*)phSrc;
    uint4 r_g0 = *(const uint4*)(gSrc + 0);
    uint4 r_g1 = *(const uint4*)(gSrc + 8);
    *(uint2*)&phiL[phOff] = r_ph;
    *(uint4*)&gL[gOff + 0] = r_g0;
    *(uint4*)&gL[gOff + 8] = r_g1;
    __syncthreads();

    v4f acc0, acc1;
    { v4f z = {}; acc0 = z; acc1 = z; }
    float lsum = 0.f;
    const v4f zf = {};

    for (int t = 0; t < 8; ++t) {            // 8 key tiles of 128
        const unsigned short* Pb = &phiL[(t & 1) * P2_SZ];
        const unsigned short* Gb = &gL[(t & 1) * G2_SZ];
        // issue next tile's global loads BEFORE compute (latency hides here)
        if (t < 7) {
            r_ph = *(const uint2*)(phSrc + (size_t)(t + 1) * 128 * 8);
            r_g0 = *(const uint4*)(gSrc + (t + 1) * 128 + 0);
            r_g1 = *(const uint4*)(gSrc + (t + 1) * 128 + 8);
        }
        // compute 8 chunks of 16 keys from LDS
        const unsigned short* pAddr = Pb + l15 * 8 + (l4 & 1) * 4;  // dup for l4>=2 (B=0 there)
        const unsigned short* gAddr = Gb + l15 * G2_STR + l4 * 4;
        #pragma unroll
        for (int kk = 0; kk < 8; ++kk) {
            const v4s aph = *(const v4s*)(pAddr + kk * 128);
            const v4s ag0 = *(const v4s*)(gAddr + kk * 16);
            const v4s ag1 = *(const v4s*)(gAddr + 16 * G2_STR + kk * 16);
            v4f s = mfma16(aph, bth, zf);
            const float e0 = __expf(s[0]), e1 = __expf(s[1]);
            const float e2 = __expf(s[2]), e3 = __expf(s[3]);
            lsum += (e0 + e1) + (e2 + e3);
            union { v4s v; unsigned u[2]; } p;
            p.u[0] = pack2bf(e0, e1);
            p.u[1] = pack2bf(e2, e3);
            acc0 = mfma16(ag0, p.v, acc0);
            acc1 = mfma16(ag1, p.v, acc1);
        }
        // write-late: next tile into the other buffer, one barrier per tile
        if (t < 7) {
            unsigned short* Pn = &phiL[((t + 1) & 1) * P2_SZ];
            unsigned short* Gn = &gL[((t + 1) & 1) * G2_SZ];
            *(uint2*)&Pn[phOff] = r_ph;
            *(uint4*)&Gn[gOff + 0] = r_g0;
            *(uint4*)&Gn[gOff + 8] = r_g1;
            __syncthreads();
        }
    }

    // --- softmax denominator: sum over the 4 l4-groups sharing query l15
    float v = lsum;
    v += __shfl_xor(v, 16);
    v += __shfl_xor(v, 32);
    const float rl = 1.0f / v;

    // --- normalize + pack O -> B-frags of the output-conv MFMA (k=c=l4*4+j)
    v4s pO0, pO1;
    {
        union { v4s v; unsigned u[2]; } p;
        p.u[0] = pack2bf(acc0[0] * rl, acc0[1] * rl);
        p.u[1] = pack2bf(acc0[2] * rl, acc0[3] * rl);
        pO0 = p.v;
        p.u[0] = pack2bf(acc1[0] * rl, acc1[1] * rl);
        p.u[1] = pack2bf(acc1[2] * rl, acc1[3] * rl);
        pO1 = p.v;
    }

    // --- output conv via 8 K=16 MFMAs + residual.  D[m=oc][n=q], bias in C.
    const size_t colq = qw + l15;
    #pragma unroll
    for (int mt = 0; mt < 4; ++mt) {
        const int oc0 = mt * 16 + l4 * 4;
        const float4 bo4 = *(const float4*)(bo + oc0);
        v4f c; c[0] = bo4.x; c[1] = bo4.y; c[2] = bo4.z; c[3] = bo4.w;
        c = mfma16(wA[mt][0], pO0, c);
        c = mfma16(wA[mt][1], pO1, c);
        const float* xr   = x   + ((size_t)(b * 64 + oc0)) * N_ + colq;
        float*       orow = out + ((size_t)(b * 64 + oc0)) * N_ + colq;
        #pragma unroll
        for (int r = 0; r < 4; ++r)
            orow[(size_t)r * N_] = gamma * c[r] + xr[(size_t)r * N_];
    }
}

// ---------------------------------------------------------------------------
extern "C" void kernel_launch(void* const* d_in, const int* in_sizes, int n_in,
                              void* d_out, int out_size, void* d_ws, size_t ws_size,
                              hipStream_t stream) {
    const float* x  = (const float*)d_in[0];
    const float* Wt = (const float*)d_in[1];
    const float* bt = (const float*)d_in[2];
    const float* Wp = (const float*)d_in[3];
    const float* bp = (const float*)d_in[4];
    const float* Wg = (const float*)d_in[5];
    const float* bg = (const float*)d_in[6];
    const float* Wo = (const float*)d_in[7];
    const float* bo = (const float*)d_in[8];
    const float* gm = (const float*)d_in[9];
    float* out = (float*)d_out;

    // workspace (bf16): thetaT [16][4096][8] | phiT [16][1024][8] | gcm [16][32][1024]
    unsigned short* thetaT = (unsigned short*)d_ws;
    unsigned short* phiT   = thetaT + (size_t)B_ * N_ * 8;
    unsigned short* gcm    = phiT   + (size_t)B_ * M_ * 8;

    hipLaunchKernelGGL(conv_pool_k, dim3(512), dim3(256), 0, stream,
                       x, Wt, bt, Wp, bp, Wg, bg, thetaT, phiT, gcm);
    hipLaunchKernelGGL(attn_k, dim3(1024), dim3(256), 0, stream,
                       x, thetaT, phiT, gcm, Wo, bo, gm, out);
}

// Round 7
// 106.314 us; speedup vs baseline: 1.9384x; 1.0485x over previous
//
#include <hip/hip_runtime.h>
#include <hip/hip_bf16.h>
#include <math.h>

#define B_ 16
#define C_ 64
#define N_ 4096   // 64*64 pixels
#define M_ 1024   // 32*32 pooled keys

typedef __attribute__((ext_vector_type(8))) short v8s;   // 8 bf16 (4 VGPRs)
typedef __attribute__((ext_vector_type(4))) short v4s;   // 4 bf16 (2 VGPRs)
typedef __attribute__((ext_vector_type(4))) float v4f;   // 4 fp32 acc

__device__ inline unsigned short f2bf(float f) {
    __hip_bfloat16 h = __float2bfloat16(f);
    return *(unsigned short*)&h;
}
__device__ inline unsigned pack2bf(float a, float b) {
    return (unsigned)f2bf(a) | ((unsigned)f2bf(b) << 16);
}
__device__ inline v8s cvt8(float4 a, float4 b) {
    union { v8s v; unsigned u[4]; } r;
    r.u[0] = pack2bf(a.x, a.y);
    r.u[1] = pack2bf(a.z, a.w);
    r.u[2] = pack2bf(b.x, b.y);
    r.u[3] = pack2bf(b.z, b.w);
    return r.v;
}
__device__ inline v4s cvt4(float4 a) {
    union { v4s v; unsigned u[2]; } r;
    r.u[0] = pack2bf(a.x, a.y);
    r.u[1] = pack2bf(a.z, a.w);
    return r.v;
}

// K=16 bf16 MFMA: A[m=l15][k=l4*4+j], B[k=l4*4+j][n=l15],
// C/D: col=l15, row=l4*4+reg (16x16-family layout).
__device__ inline v4f mfma16(v4s a, v4s b, v4f c) {
#if __has_builtin(__builtin_amdgcn_mfma_f32_16x16x16bf16_1k)
    return __builtin_amdgcn_mfma_f32_16x16x16bf16_1k(a, b, c, 0, 0, 0);
#else
    v4f d;
    asm("v_mfma_f32_16x16x16_bf16 %0, %1, %2, %3\n\ts_nop 7\n\ts_nop 7"
        : "=&v"(d) : "v"(a), "v"(b), "v"(c));
    return d;
#endif
}

// ---------------------------------------------------------------------------
// Kernel 1: EXACT revert to the R4 conv (best measured total: 108.75us).
// R6's LDS x-staging was neutral-to-negative -> conv is not load-latency
// bound; direct strided loads with 2 waves/SIMD stay.
// ---------------------------------------------------------------------------
#define SP2 66   // sPool row stride (floats)

__global__ __launch_bounds__(256, 2) void conv_pool_k(
    const float* __restrict__ x,
    const float* __restrict__ Wt, const float* __restrict__ bt,
    const float* __restrict__ Wp, const float* __restrict__ bp,
    const float* __restrict__ Wg, const float* __restrict__ bg,
    unsigned short* __restrict__ thetaT,
    unsigned short* __restrict__ phiT,
    unsigned short* __restrict__ gcm)
{
    __shared__ float sPool[80 * SP2];   // 40 ch x 2 rows = 80 rows, 21.1 KB

    const int tid  = threadIdx.x;
    const int lane = tid & 63;
    const int wid  = tid >> 6;
    const int l15  = lane & 15;
    const int l4   = lane >> 4;

    const int b  = blockIdx.x >> 5;
    const int y0 = (blockIdx.x & 31) << 1;   // first of 2 image rows
    const int y  = y0 + (wid >> 1);          // this wave's row
    const int xh = (wid & 1) * 32;           // this wave's half-row

    // --- A-fragments: weights, 3 m-tiles x 2 k-halves (bf16, loaded once)
    const float* row0 = (l15 < 8) ? (Wt + l15 * 64) : (Wp + (l15 - 8) * 64);
    const float* row1 = Wg + l15 * 64;
    const float* row2 = Wg + (16 + l15) * 64;
    v8s afrag[3][2];
    #pragma unroll
    for (int kh = 0; kh < 2; ++kh) {
        const int c0 = kh * 32 + l4 * 8;
        afrag[0][kh] = cvt8(*(const float4*)(row0 + c0), *(const float4*)(row0 + c0 + 4));
        afrag[1][kh] = cvt8(*(const float4*)(row1 + c0), *(const float4*)(row1 + c0 + 4));
        afrag[2][kh] = cvt8(*(const float4*)(row2 + c0), *(const float4*)(row2 + c0 + 4));
    }

    // --- accumulators init = bias (C-layout: row o = l4*4+r)
    v4f acc[2][3];
    {
        float bv[3][4];
        #pragma unroll
        for (int r = 0; r < 4; ++r) {
            const int o = l4 * 4 + r;               // 0..15
            bv[0][r] = (o < 8) ? bt[o] : bp[o - 8];
            bv[1][r] = bg[o];
            bv[2][r] = bg[16 + o];
        }
        #pragma unroll
        for (int nt = 0; nt < 2; ++nt)
            #pragma unroll
            for (int t = 0; t < 3; ++t) {
                v4f a; a[0] = bv[t][0]; a[1] = bv[t][1];
                a[2] = bv[t][2]; a[3] = bv[t][3];
                acc[nt][t] = a;
            }
    }

    // --- main GEMM: 2 n-tiles x 2 k-halves x 3 m-tiles
    const float* xb = x + (size_t)b * C_ * N_ + y * 64;
    #pragma unroll
    for (int nt = 0; nt < 2; ++nt) {
        const int n0 = xh + nt * 16 + l15;
        #pragma unroll
        for (int kh = 0; kh < 2; ++kh) {
            const int cb = kh * 32 + l4 * 8;
            float f[8];
            #pragma unroll
            for (int j = 0; j < 8; ++j) f[j] = xb[(size_t)(cb + j) * N_ + n0];
            union { v8s v; unsigned u[4]; } bf;
            #pragma unroll
            for (int j = 0; j < 4; ++j) bf.u[j] = pack2bf(f[2*j], f[2*j+1]);
            #pragma unroll
            for (int t = 0; t < 3; ++t)
                acc[nt][t] = __builtin_amdgcn_mfma_f32_16x16x32_bf16(
                    afrag[t][kh], bf.v, acc[nt][t], 0, 0, 0);
        }
    }

    // --- theta: straight from C-regs (rows 0..7 of m-tile 0 = lanes l4<2)
    #pragma unroll
    for (int nt = 0; nt < 2; ++nt) {
        if (l4 < 2) {
            const int n = y * 64 + xh + nt * 16 + l15;
            const unsigned lo = pack2bf(acc[nt][0][0], acc[nt][0][1]);
            const unsigned hi = pack2bf(acc[nt][0][2], acc[nt][0][3]);
            *(uint2*)(thetaT + ((size_t)b * N_ + n) * 8 + l4 * 4) = make_uint2(lo, hi);
        }
    }

    // --- stage phi/g to LDS for pooling: row index = ch*2 + (image row in pair)
    {
        const int rr = wid >> 1;   // 0/1: which row of the pair
        #pragma unroll
        for (int nt = 0; nt < 2; ++nt) {
            const int px = xh + nt * 16 + l15;      // 0..63
            if (l4 >= 2) {                          // phi: ch = (l4-2)*4 + r
                #pragma unroll
                for (int r = 0; r < 4; ++r)
                    sPool[(((l4 - 2) * 4 + r) * 2 + rr) * SP2 + px] = acc[nt][0][r];
            }
            #pragma unroll
            for (int r = 0; r < 4; ++r) {
                sPool[((8  + l4 * 4 + r) * 2 + rr) * SP2 + px] = acc[nt][1][r];
                sPool[((24 + l4 * 4 + r) * 2 + rr) * SP2 + px] = acc[nt][2][r];
            }
        }
    }
    __syncthreads();

    // --- 2x2 maxpool + store: 40 ch x 32 pooled px per block
    {
        const int pc  = tid & 31;          // pooled col
        const int grp = tid >> 5;          // 8 groups x 5 channels
        const int mg  = (y0 >> 1) * 32 + pc;
        #pragma unroll
        for (int i = 0; i < 5; ++i) {
            const int ch = grp * 5 + i;
            const float* s0 = sPool + (ch * 2 + 0) * SP2 + pc * 2;
            const float* s1 = sPool + (ch * 2 + 1) * SP2 + pc * 2;
            const float v = fmaxf(fmaxf(s0[0], s0[1]), fmaxf(s1[0], s1[1]));
            if (ch < 8) phiT[((size_t)b * M_ + mg) * 8 + ch] = f2bf(v);
            else        gcm[((size_t)(b * 32 + ch - 8)) * M_ + mg] = f2bf(v);
        }
    }
}

// ---------------------------------------------------------------------------
// Kernel 2 (round 11): KEY-SPLIT attention — breaks the 4-chain invariant.
// R3/R4 proved concurrency/SIMD is stuck at 4 for any (waves x q-streams)
// split when each chain owns all 1024 keys.  Now each q-group's keys are
// split across TWO partner waves (512 keys each); partials (acc0,acc1,lsum)
// merge through LDS at the end (softmax denom and PV are linear -> exact).
// Block = 512 thr: 4 q-groups x 2 key-halves; grid 1024 -> 8192 waves =
// 8 waves/SIMD (2x R4), launch_bounds(512,8) (attn has held VGPR=64 for six
// rounds; Wo/bo moved post-merge to keep the loop lean).  Each half single-
// buffers its own phi/g tiles (4 tiles of 128 keys; 2 barriers/tile; global
// prefetch into regs still issued before compute).  LDS 30.6KB -> 4 blk/CU.
// Inner math/fragments byte-identical to proven R4.
// ---------------------------------------------------------------------------
#define P2_SZ  (128 * 8)      // shorts per phi buffer (row = 8 shorts)
#define G2_STR 136            // g row stride in shorts (272 B -> 2-way banks)
#define G2_SZ  (32 * G2_STR)  // shorts per g buffer

__global__ __launch_bounds__(512, 8) void attn_k(
    const float* __restrict__ x,
    const unsigned short* __restrict__ thetaT,
    const unsigned short* __restrict__ phiT,
    const unsigned short* __restrict__ gcm,
    const float* __restrict__ Wo, const float* __restrict__ bo,
    const float* __restrict__ gammap,
    float* __restrict__ out)
{
    __shared__ unsigned short phiL[2][P2_SZ];   // 4 KB   (one buf per half)
    __shared__ unsigned short gL[2][G2_SZ];     // 17.4 KB
    __shared__ float sMrg[4][64][9];            // 9.2 KB partial merge

    const int tid  = threadIdx.x;
    const int lane = tid & 63;
    const int wid  = tid >> 6;          // 0..7
    const int l15  = lane & 15;
    const int l4   = lane >> 4;
    const int half = tid >> 8;          // 0: keys 0-511, 1: keys 512-1023
    const int htid = tid & 255;         // thread index within half

    const int b  = blockIdx.x >> 6;
    const int qw = ((blockIdx.x & 63) << 6) + (wid & 3) * 16;  // 16 q/wave

    // --- theta B-frag (K=16: k=ch l4*4+j, real for l4<2, zero else)
    v4s bth; { v4s z = {}; bth = z; }
    if (l4 < 2)
        bth = *(const v4s*)(thetaT + ((size_t)b * N_ + qw + l15) * 8 + l4 * 4);

    // --- staging addresses (per thread, own half's key range)
    const size_t kbase = (size_t)half * 512;
    const unsigned short* phSrc = phiT + ((size_t)b * M_ + kbase + (htid >> 1)) * 8 + (htid & 1) * 4;
    const int phOff = (htid >> 1) * 8 + (htid & 1) * 4;
    const int gch = htid >> 3, gseg = (htid & 7) * 16;
    const unsigned short* gSrc = gcm + ((size_t)(b * 32 + gch)) * M_ + kbase + gseg;
    const int gOff = gch * G2_STR + gseg;

    // --- prologue: load + write tile 0 of own half
    uint2 r_ph = *(const uint2*)phSrc;
    uint4 r_g0 = *(const uint4*)(gSrc + 0);
    uint4 r_g1 = *(const uint4*)(gSrc + 8);
    *(uint2*)&phiL[half][phOff] = r_ph;
    *(uint4*)&gL[half][gOff + 0] = r_g0;
    *(uint4*)&gL[half][gOff + 8] = r_g1;
    __syncthreads();

    v4f acc0, acc1;
    { v4f z = {}; acc0 = z; acc1 = z; }
    float lsum = 0.f;
    const v4f zf = {};

    for (int t = 0; t < 4; ++t) {            // 4 key tiles of 128 (own half)
        // issue next tile's global loads BEFORE compute (latency hides here)
        if (t < 3) {
            r_ph = *(const uint2*)(phSrc + (size_t)(t + 1) * 128 * 8);
            r_g0 = *(const uint4*)(gSrc + (t + 1) * 128 + 0);
            r_g1 = *(const uint4*)(gSrc + (t + 1) * 128 + 8);
        }
        // compute 8 chunks of 16 keys from LDS
        const unsigned short* pAddr = &phiL[half][l15 * 8 + (l4 & 1) * 4];  // dup for l4>=2 (B=0)
        const unsigned short* gAddr = &gL[half][l15 * G2_STR + l4 * 4];
        #pragma unroll
        for (int kk = 0; kk < 8; ++kk) {
            const v4s aph = *(const v4s*)(pAddr + kk * 128);
            const v4s ag0 = *(const v4s*)(gAddr + kk * 16);
            const v4s ag1 = *(const v4s*)(gAddr + 16 * G2_STR + kk * 16);
            v4f s = mfma16(aph, bth, zf);
            const float e0 = __expf(s[0]), e1 = __expf(s[1]);
            const float e2 = __expf(s[2]), e3 = __expf(s[3]);
            lsum += (e0 + e1) + (e2 + e3);
            union { v4s v; unsigned u[2]; } p;
            p.u[0] = pack2bf(e0, e1);
            p.u[1] = pack2bf(e2, e3);
            acc0 = mfma16(ag0, p.v, acc0);
            acc1 = mfma16(ag1, p.v, acc1);
        }
        // single-buffered tiles: barrier (reads done) -> write t+1 -> barrier
        if (t < 3) {
            __syncthreads();
            *(uint2*)&phiL[half][phOff] = r_ph;
            *(uint4*)&gL[half][gOff + 0] = r_g0;
            *(uint4*)&gL[half][gOff + 8] = r_g1;
            __syncthreads();
        }
    }

    // --- merge key-halves: half B publishes partials, half A combines
    if (half == 1) {
        float* m = sMrg[wid & 3][lane];
        m[0] = acc0[0]; m[1] = acc0[1]; m[2] = acc0[2]; m[3] = acc0[3];
        m[4] = acc1[0]; m[5] = acc1[1]; m[6] = acc1[2]; m[7] = acc1[3];
        m[8] = lsum;
    }
    __syncthreads();
    if (half == 1) return;                   // no barriers below this point
    {
        const float* m = sMrg[wid][lane];
        acc0[0] += m[0]; acc0[1] += m[1]; acc0[2] += m[2]; acc0[3] += m[3];
        acc1[0] += m[4]; acc1[1] += m[5]; acc1[2] += m[6]; acc1[3] += m[7];
        lsum += m[8];
    }

    // --- softmax denominator: sum over the 4 l4-groups sharing query l15
    float v = lsum;
    v += __shfl_xor(v, 16);
    v += __shfl_xor(v, 32);
    const float rl = 1.0f / v;

    // --- normalize + pack O -> B-frags of the output-conv MFMA (k=c=l4*4+j)
    v4s pO0, pO1;
    {
        union { v4s v; unsigned u[2]; } p;
        p.u[0] = pack2bf(acc0[0] * rl, acc0[1] * rl);
        p.u[1] = pack2bf(acc0[2] * rl, acc0[3] * rl);
        pO0 = p.v;
        p.u[0] = pack2bf(acc1[0] * rl, acc1[1] * rl);
        p.u[1] = pack2bf(acc1[2] * rl, acc1[3] * rl);
        pO1 = p.v;
    }

    // --- output conv via 8 K=16 MFMAs + residual.  Wo/bo loaded here
    // (post-merge, off the main loop's register budget).  D[m=oc][n=q].
    const float gamma = *gammap;
    const size_t colq = qw + l15;
    #pragma unroll
    for (int mt = 0; mt < 4; ++mt) {
        const int oc0 = mt * 16 + l4 * 4;
        const float4 w0 = *(const float4*)(Wo + (mt * 16 + l15) * 32 + l4 * 4);
        const float4 w1 = *(const float4*)(Wo + (mt * 16 + l15) * 32 + 16 + l4 * 4);
        const float4 bo4 = *(const float4*)(bo + oc0);
        v4f c; c[0] = bo4.x; c[1] = bo4.y; c[2] = bo4.z; c[3] = bo4.w;
        c = mfma16(cvt4(w0), pO0, c);
        c = mfma16(cvt4(w1), pO1, c);
        const float* xr   = x   + ((size_t)(b * 64 + oc0)) * N_ + colq;
        float*       orow = out + ((size_t)(b * 64 + oc0)) * N_ + colq;
        #pragma unroll
        for (int r = 0; r < 4; ++r)
            orow[(size_t)r * N_] = gamma * c[r] + xr[(size_t)r * N_];
    }
}

// ---------------------------------------------------------------------------
extern "C" void kernel_launch(void* const* d_in, const int* in_sizes, int n_in,
                              void* d_out, int out_size, void* d_ws, size_t ws_size,
                              hipStream_t stream) {
    const float* x  = (const float*)d_in[0];
    const float* Wt = (const float*)d_in[1];
    const float* bt = (const float*)d_in[2];
    const float* Wp = (const float*)d_in[3];
    const float* bp = (const float*)d_in[4];
    const float* Wg = (const float*)d_in[5];
    const float* bg = (const float*)d_in[6];
    const float* Wo = (const float*)d_in[7];
    const float* bo = (const float*)d_in[8];
    const float* gm = (const float*)d_in[9];
    float* out = (float*)d_out;

    // workspace (bf16): thetaT [16][4096][8] | phiT [16][1024][8] | gcm [16][32][1024]
    unsigned short* thetaT = (unsigned short*)d_ws;
    unsigned short* phiT   = thetaT + (size_t)B_ * N_ * 8;
    unsigned short* gcm    = phiT   + (size_t)B_ * M_ * 8;

    hipLaunchKernelGGL(conv_pool_k, dim3(512), dim3(256), 0, stream,
                       x, Wt, bt, Wp, bp, Wg, bg, thetaT, phiT, gcm);
    hipLaunchKernelGGL(attn_k, dim3(1024), dim3(512), 0, stream,
                       x, thetaT, phiT, gcm, Wo, bo, gm, out);
}